// Round 12
// baseline (148.676 us; speedup 1.0000x reference)
//
#include <hip/hip_runtime.h>

#define B_   4
#define C_   256
#define C8_  32
#define N_   4096
#define JS   4                 // key split: js0 -> fp32 in d_out, js1-3 -> bf16 pnum
#define NJ4  (N_ / JS)         // 1024 keys per attn block
#define KB2  128               // j per tile
#define NT4  (NJ4 / KB2)       // 8 j-tiles per attn block
#define SUBT 8192              // shorts per V subtile: 256 c x 32 j
#define BCN  ((size_t)B_ * C_ * N_)   // 4,194,304

typedef __attribute__((ext_vector_type(8))) short bf16x8;
typedef __attribute__((ext_vector_type(4))) float f32x4;

__device__ inline short f2bf(float f) {
    union { float f; unsigned u; } v; v.f = f;
    unsigned r = v.u + 0x7FFFu + ((v.u >> 16) & 1u);   // RNE
    return (short)(r >> 16);
}
__device__ inline float bf2f(short s) {
    union { unsigned u; float f; } v; v.u = ((unsigned)(unsigned short)s) << 16;
    return v.f;
}

// ---------------------------------------------------------------------------
// Kernel 0: prep (tiny). blocks [0,40): W fp32 -> fragment-packed Wall.
// block 40: bias gather ball[320]. (Unchanged from R10/R11 bench.)
// ---------------------------------------------------------------------------
__global__ __launch_bounds__(256) void prep_kernel(
    const float* __restrict__ Wq, const float* __restrict__ bq,
    const float* __restrict__ Wk, const float* __restrict__ bk,
    const float* __restrict__ Wv, const float* __restrict__ bv,
    short* __restrict__ Wall, float* __restrict__ ball)
{
    const int blk = blockIdx.x;
    const int t   = threadIdx.x;
    if (blk < 40) {
        const int base = blk * 2048 + t * 8;            // 40*2048 = 320*256
        const int r = base >> 8, cc = base & 255;       // cc is 8-aligned
        const float* src = (r < 32) ? &Wq[r * C_ + cc]
                         : (r < 64) ? &Wk[(r - 32) * C_ + cc]
                                    : &Wv[(r - 64) * C_ + cc];
        const float4 a  = *(const float4*)src;
        const float4 b4 = *(const float4*)(src + 4);
        short4 s1, s2;
        s1.x = f2bf(a.x);  s1.y = f2bf(a.y);  s1.z = f2bf(a.z);  s1.w = f2bf(a.w);
        s2.x = f2bf(b4.x); s2.y = f2bf(b4.y); s2.z = f2bf(b4.z); s2.w = f2bf(b4.w);
        const int gct = r >> 4, l16w = r & 15;
        const int k   = cc >> 5, quad = (cc >> 3) & 3;
        short* d = &Wall[(((size_t)(gct * 8 + k) * 4 + quad) * 16 + l16w) * 8];
        *(short4*)d       = s1;
        *(short4*)(d + 4) = s2;
    } else {
        for (int i = t; i < 320; i += 256)
            ball[i] = (i < 32) ? bq[i] : (i < 64) ? bk[i - 32] : bv[i - 64];
    }
}

// ---------------------------------------------------------------------------
// Kernel 1: FUSED transpose + MFMA projections (unchanged from R10/R11 bench).
// ---------------------------------------------------------------------------
#define VSTORE(A, CT)                                                         \
  {                                                                           \
    const int co   = (CT) * 16 + l16;                                         \
    const float bs = ball[co];                                                \
    const int nb   = n0 + nw * 16 + quad * 4;                                 \
    const int js   = nb >> 11, sub = (nb >> 5) & 63, jj = nb & 31;            \
    short4 s;                                                                 \
    s.x = f2bf(A[0] + bs); s.y = f2bf(A[1] + bs);                             \
    s.z = f2bf(A[2] + bs); s.w = f2bf(A[3] + bs);                             \
    *(short4*)&vws[((size_t)((b * 2 + js) * 64 + sub)) * SUBT                 \
                   + (co - 64) * 32 + jj] = s;                                \
  }

__global__ __launch_bounds__(1024) void proj_kernel(
    const float* __restrict__ x, const short* __restrict__ Wall,
    const float* __restrict__ ball,
    short* __restrict__ qws, short* __restrict__ kws, short* __restrict__ vws)
{
    __shared__ short tilebf[256 * 68];   // 34.8 KB

    const int n0 = blockIdx.x * 64;
    const int b  = blockIdx.y;
    const int t  = threadIdx.x;
    const int w  = t >> 6, lane = t & 63, l16 = lane & 15, quad = lane >> 4;
    const int nw = w & 3, qtr = w >> 2;

    // phase 1: x (fp32) -> bf16 LDS tile [c][nl], 4 float4 per thread
    const float* xb = x + (size_t)b * C_ * N_ + n0;
    #pragma unroll
    for (int i = 0; i < 4; i++) {
        int e = t + i * 1024;                // 4096 float4 = 256 rows x 16
        int c = e >> 4, n4 = (e & 15) * 4;
        float4 v = *(const float4*)(xb + (size_t)c * N_ + n4);
        short4 s;
        s.x = f2bf(v.x); s.y = f2bf(v.y); s.z = f2bf(v.z); s.w = f2bf(v.w);
        *(short4*)&tilebf[c * 68 + n4] = s;
    }
    __syncthreads();

    // phase 2: bfr fragments (n = n0 + nw*16 + l16; c = k*32 + quad*8 + j)
    bf16x8 bfr[8];
    const int nl = nw * 16 + l16;
    #pragma unroll
    for (int k = 0; k < 8; k++) {
        bf16x8 f;
        #pragma unroll
        for (int j = 0; j < 8; j++)
            f[j] = tilebf[(k * 32 + quad * 8 + j) * 68 + nl];
        bfr[k] = f;
    }

    f32x4 acc[5];
    #pragma unroll
    for (int i = 0; i < 5; i++) acc[i] = (f32x4){0.f, 0.f, 0.f, 0.f};

    if (qtr == 0) {
        #pragma unroll
        for (int k = 0; k < 8; k++) {
            const bf16x8 bk = bfr[k];
            #pragma unroll
            for (int c5 = 0; c5 < 4; c5++) {
                const bf16x8 af = *(const bf16x8*)
                    &Wall[(size_t)(c5 * 8 + k) * 512 + lane * 8];
                acc[c5] = __builtin_amdgcn_mfma_f32_16x16x32_bf16(af, bk, acc[c5], 0, 0, 0);
            }
            const bf16x8 af4 = *(const bf16x8*)
                &Wall[(size_t)(4 * 8 + k) * 512 + lane * 8];
            acc[4] = __builtin_amdgcn_mfma_f32_16x16x32_bf16(bk, af4, acc[4], 0, 0, 0);
        }
    } else {
        const int ct0 = qtr * 5;
        #pragma unroll
        for (int k = 0; k < 8; k++) {
            const bf16x8 bk = bfr[k];
            #pragma unroll
            for (int c5 = 0; c5 < 5; c5++) {
                const bf16x8 af = *(const bf16x8*)
                    &Wall[(size_t)((ct0 + c5) * 8 + k) * 512 + lane * 8];
                acc[c5] = __builtin_amdgcn_mfma_f32_16x16x32_bf16(bk, af, acc[c5], 0, 0, 0);
            }
        }
    }

    const int grp = (n0 >> 4) + nw;          // = n>>4 for this wave

    if (qtr == 0) {
        #pragma unroll
        for (int ct = 0; ct < 2; ct++) {
            const int cb = ct * 16 + quad * 4;
            short4 s;
            s.x = f2bf(acc[ct][0] + ball[cb + 0]);
            s.y = f2bf(acc[ct][1] + ball[cb + 1]);
            s.z = f2bf(acc[ct][2] + ball[cb + 2]);
            s.w = f2bf(acc[ct][3] + ball[cb + 3]);
            *(short4*)&qws[((size_t)(b * 256 + grp)) * 512
                           + (ct * 2 + (quad >> 1)) * 128 + l16 * 8 + (quad & 1) * 4] = s;
        }
        #pragma unroll
        for (int ct = 2; ct < 4; ct++) {
            const int cb = ct * 16 + quad * 4;
            short4 s;
            s.x = f2bf(acc[ct][0] + ball[cb + 0]);
            s.y = f2bf(acc[ct][1] + ball[cb + 1]);
            s.z = f2bf(acc[ct][2] + ball[cb + 2]);
            s.w = f2bf(acc[ct][3] + ball[cb + 3]);
            *(short4*)&kws[((size_t)(b * 256 + grp)) * 512
                           + ((ct - 2) * 2 + (quad >> 1)) * 128 + l16 * 8 + (quad & 1) * 4] = s;
        }
        VSTORE(acc[4], 4);
    } else {
        const int ct0 = qtr * 5;
        #pragma unroll
        for (int c5 = 0; c5 < 5; c5++) VSTORE(acc[c5], ct0 + c5);
    }
}

// ---------------------------------------------------------------------------
// Kernel 2: MFMA flash attention, v13: 4-way key split = BOTH proven levers.
// 512 blocks (4b x 4js x 32qc) x 512 thr, 128 q x 1024 keys each ->
// V traffic stays 256 MB (v12's optimum) AND 2 blocks/CU (v10's occupancy):
// when block A's waves sit in exp/pack/barrier, block B's feed MFMA/LDS
// (m114 cross-wave overlap) -- v12's phase-locked 1-block/CU was the
// dominant stall (period 7330 cy vs ~2300 of pipe work). TILE_BODY,
// swizzle, per-wave MFMA count/order all unchanged from the benched v12.
// Partials: js0 -> fp32 out; js1-3 -> bf16 pnum[0..2]; pl[4][16384].
// ---------------------------------------------------------------------------
#define TILE_BODY(TILE, KC, KN, BUF)                                          \
  {                                                                           \
    const short* vb = vbase + (size_t)(TILE) * 4 * SUBT;                      \
    bf16x8 vf0[2], vf1[2];                                                    \
    _Pragma("unroll") for (int ct = 0; ct < 2; ct++)                          \
      vf0[ct] = *(const bf16x8*)(vb + 0 * SUBT + (ct*16+l16)*32 + quad*8);    \
    _Pragma("unroll") for (int ct = 0; ct < 2; ct++)                          \
      vf1[ct] = *(const bf16x8*)(vb + 1 * SUBT + (ct*16+l16)*32 + quad*8);    \
    f32x4 s[8];                                                               \
    _Pragma("unroll") for (int jf = 0; jf < 8; jf++)                          \
      s[jf] = __builtin_amdgcn_mfma_f32_16x16x32_bf16(KC[jf], qf,             \
              (f32x4){0.f,0.f,0.f,0.f}, 0, 0, 0);                             \
    {                                                                         \
      const int tn = ((TILE) + 1 < NT4) ? (TILE) + 1 : (TILE);                \
      const short* kb = kfb + (size_t)(tn * 8) * 512;                         \
      _Pragma("unroll") for (int jf = 0; jf < 8; jf++)                        \
        KN[jf] = *(const bf16x8*)(kb + (size_t)jf * 512 + lane * 8);          \
    }                                                                         \
    _Pragma("unroll") for (int jf = 0; jf < 8; jf++) {                        \
      float p0 = __expf(s[jf][0]); float p1 = __expf(s[jf][1]);               \
      float p2 = __expf(s[jf][2]); float p3 = __expf(s[jf][3]);               \
      lsum += p0 + p1 + p2 + p3;                                              \
      short4 pa; pa.x = f2bf(p0); pa.y = f2bf(p1);                            \
      pa.z = f2bf(p2); pa.w = f2bf(p3);                                       \
      const int u = (jf * 2 + (quad >> 1)) ^ swz;                             \
      *(short4*)&Plds[BUF][prowW + u * 8] = pa;                               \
    }                                                                         \
    asm volatile("s_waitcnt lgkmcnt(0)" ::: "memory");                        \
    __builtin_amdgcn_s_barrier();                                             \
    asm volatile("" ::: "memory");                                            \
    bf16x8 vf2[2];                                                            \
    _Pragma("unroll") for (int ct = 0; ct < 2; ct++)                          \
      vf2[ct] = *(const bf16x8*)(vb + 2 * SUBT + (ct*16+l16)*32 + quad*8);    \
    __builtin_amdgcn_s_setprio(1);                                            \
    _Pragma("unroll") for (int qt = 0; qt < 8; ++qt) {                        \
      const bf16x8 pf = *(const bf16x8*)                                      \
        &Plds[BUF][(qt*16+l16)*128 + ((0*4+quad)^swz)*8];                     \
      _Pragma("unroll") for (int ct = 0; ct < 2; ++ct)                        \
        acc[ct][qt] = __builtin_amdgcn_mfma_f32_16x16x32_bf16(                \
            vf0[ct], pf, acc[ct][qt], 0, 0, 0);                               \
    }                                                                         \
    bf16x8 vf3[2];                                                            \
    _Pragma("unroll") for (int ct = 0; ct < 2; ct++)                          \
      vf3[ct] = *(const bf16x8*)(vb + 3 * SUBT + (ct*16+l16)*32 + quad*8);    \
    _Pragma("unroll") for (int qt = 0; qt < 8; ++qt) {                        \
      const bf16x8 pf = *(const bf16x8*)                                      \
        &Plds[BUF][(qt*16+l16)*128 + ((1*4+quad)^swz)*8];                     \
      _Pragma("unroll") for (int ct = 0; ct < 2; ++ct)                        \
        acc[ct][qt] = __builtin_amdgcn_mfma_f32_16x16x32_bf16(                \
            vf1[ct], pf, acc[ct][qt], 0, 0, 0);                               \
    }                                                                         \
    _Pragma("unroll") for (int qt = 0; qt < 8; ++qt) {                        \
      const bf16x8 pf = *(const bf16x8*)                                      \
        &Plds[BUF][(qt*16+l16)*128 + ((2*4+quad)^swz)*8];                     \
      _Pragma("unroll") for (int ct = 0; ct < 2; ++ct)                        \
        acc[ct][qt] = __builtin_amdgcn_mfma_f32_16x16x32_bf16(                \
            vf2[ct], pf, acc[ct][qt], 0, 0, 0);                               \
    }                                                                         \
    _Pragma("unroll") for (int qt = 0; qt < 8; ++qt) {                        \
      const bf16x8 pf = *(const bf16x8*)                                      \
        &Plds[BUF][(qt*16+l16)*128 + ((3*4+quad)^swz)*8];                     \
      _Pragma("unroll") for (int ct = 0; ct < 2; ++ct)                        \
        acc[ct][qt] = __builtin_amdgcn_mfma_f32_16x16x32_bf16(                \
            vf3[ct], pf, acc[ct][qt], 0, 0, 0);                               \
    }                                                                         \
    __builtin_amdgcn_s_setprio(0);                                            \
  }

__global__ __launch_bounds__(512, 2) void attn_kernel(
    const short* __restrict__ qws, const short* __restrict__ kws,
    const short* __restrict__ vws,
    float* __restrict__ out, short* __restrict__ pnum, float* __restrict__ pl)
{
    __shared__ short Plds[2][128 * 128];   // 2 x 32 KB (2 blocks/CU -> 128 KB)

    const int blk = blockIdx.x;
    const int b   = blk & 3;
    const int js  = (blk >> 2) & 3;
    const int qc  = blk >> 4;            // 0..31, 128 q each
    const int t   = threadIdx.x;
    const int w   = t >> 6, lane = t & 63, l16 = lane & 15, quad = lane >> 4;
    const int q   = qc * 128 + w * 16 + l16;   // QK-duty q row for this lane

    // Q from fragment-packed qws: group qc*8+w, contiguous 1KB per wave
    const bf16x8 qf = *(const bf16x8*)
        &qws[((size_t)(b * 256 + qc * 8 + w)) * 512 + lane * 8];

    f32x4 acc[2][8];                     // PV: wave owns c [32w,32w+32) x 128 q
    #pragma unroll
    for (int i = 0; i < 2; i++)
        #pragma unroll
        for (int j = 0; j < 8; j++) acc[i][j] = (f32x4){0.f, 0.f, 0.f, 0.f};
    float lsum = 0.f;

    // fragment-packed K base for this (b, js-quarter): groups js*64 .. +64
    const short* kfb = kws + ((size_t)(b * 256 + js * 64)) * 512;
    // tiled V: quarter js covers subtiles [(js&1)*32, +32) of half js>>1
    const short* vbase = vws
        + ((size_t)((b * 2 + (js >> 1)) * 64 + (js & 1) * 32)) * SUBT
        + w * 32 * 32;

    // swizzle: 16B unit u' = u ^ (row&7); row&7 == l16&7 for write and reads
    const int swz   = l16 & 7;
    const int prowW = (w * 16 + l16) * 128 + (quad & 1) * 4;   // + u'*8

    // prologue: kf for tile 0 (8 j-frags x K=32), ping buffer
    bf16x8 kfA[8], kfB[8];
    #pragma unroll
    for (int jf = 0; jf < 8; jf++)
        kfA[jf] = *(const bf16x8*)(kfb + (size_t)jf * 512 + lane * 8);

    #pragma unroll 1
    for (int tile = 0; tile < NT4; tile += 2) {
        TILE_BODY(tile,     kfA, kfB, 0);
        TILE_BODY(tile + 1, kfB, kfA, 1);
    }

    // denominator partial for this wave's q over its j quarter
    lsum += __shfl_xor(lsum, 16, 64);
    lsum += __shfl_xor(lsum, 32, 64);
    if (quad == 0) pl[(size_t)js * 16384 + (size_t)b * N_ + q] = lsum;

    // numerator partial: js0 -> fp32 into out, js1-3 -> bf16 into pnum[js-1]
    const int qq = qc * 128 + l16;
    if (js == 0) {
        float* ob = out + (size_t)b * C_ * N_;
        #pragma unroll
        for (int ct = 0; ct < 2; ++ct)
            #pragma unroll
            for (int qt = 0; qt < 8; ++qt)
                #pragma unroll
                for (int r = 0; r < 4; ++r) {
                    const int c = w * 32 + ct * 16 + quad * 4 + r;
                    ob[(size_t)c * N_ + qq + qt * 16] = acc[ct][qt][r];
                }
    } else {
        short* pb1 = pnum + (size_t)(js - 1) * BCN + (size_t)b * C_ * N_;
        #pragma unroll
        for (int ct = 0; ct < 2; ++ct)
            #pragma unroll
            for (int qt = 0; qt < 8; ++qt)
                #pragma unroll
                for (int r = 0; r < 4; ++r) {
                    const int c = w * 32 + ct * 16 + quad * 4 + r;
                    pb1[(size_t)c * N_ + qq + qt * 16] = f2bf(acc[ct][qt][r]);
                }
    }
}

// ---------------------------------------------------------------------------
// Kernel 3: combine: linv = 1/(pl0+pl1+pl2+pl3) inline (R2-benched 4-way
// denominator form); out = g*(out + p1 + p2 + p3)*linv + x.
// ---------------------------------------------------------------------------
__global__ __launch_bounds__(256) void combine_kernel(
    const short* __restrict__ pnum, const float* __restrict__ pl,
    const float* __restrict__ x, const float* __restrict__ gamma,
    float* __restrict__ out)
{
    const size_t i4 = ((size_t)blockIdx.x * 256 + threadIdx.x) * 4;   // < BCN
    const float4 nv = *(const float4*)(out + i4);
    const short4 n1 = *(const short4*)(pnum + i4);
    const short4 n2 = *(const short4*)(pnum + BCN + i4);
    const short4 n3 = *(const short4*)(pnum + 2 * BCN + i4);
    const float4 xv = *(const float4*)(x + i4);
    const int   bn  = (int)((i4 >> 20) * 4096 + (i4 & 4095));         // b*N + n
    const float4 p0 = *(const float4*)(pl + bn);
    const float4 p1 = *(const float4*)(pl + 16384 + bn);
    const float4 p2 = *(const float4*)(pl + 32768 + bn);
    const float4 p3 = *(const float4*)(pl + 49152 + bn);
    float4 lv;
    lv.x = 1.0f / (p0.x + p1.x + p2.x + p3.x);
    lv.y = 1.0f / (p0.y + p1.y + p2.y + p3.y);
    lv.z = 1.0f / (p0.z + p1.z + p2.z + p3.z);
    lv.w = 1.0f / (p0.w + p1.w + p2.w + p3.w);
    const float g0 = gamma[0];
    float4 o;
    o.x = g0 * ((nv.x + bf2f(n1.x) + bf2f(n2.x) + bf2f(n3.x)) * lv.x) + xv.x;
    o.y = g0 * ((nv.y + bf2f(n1.y) + bf2f(n2.y) + bf2f(n3.y)) * lv.y) + xv.y;
    o.z = g0 * ((nv.z + bf2f(n1.z) + bf2f(n2.z) + bf2f(n3.z)) * lv.z) + xv.z;
    o.w = g0 * ((nv.w + bf2f(n1.w) + bf2f(n2.w) + bf2f(n3.w)) * lv.w) + xv.w;
    *(float4*)(out + i4) = o;
}

extern "C" void kernel_launch(void* const* d_in, const int* in_sizes, int n_in,
                              void* d_out, int out_size, void* d_ws, size_t ws_size,
                              hipStream_t stream)
{
    const float* x     = (const float*)d_in[0];
    const float* Wq    = (const float*)d_in[1];
    const float* bq    = (const float*)d_in[2];
    const float* Wk    = (const float*)d_in[3];
    const float* bk    = (const float*)d_in[4];
    const float* Wv    = (const float*)d_in[5];
    const float* bv    = (const float*)d_in[6];
    const float* gamma = (const float*)d_in[7];
    float* out = (float*)d_out;

    // ws layout, 35.7 MiB total. ws_size evidence: the harness's workspace
    // fill dispatch writes 256 MiB (R11 trace) -> 36 MiB is safe.
    char* base = (char*)d_ws;
    short* vws   = (short*)(base);                      // 8 MB   [8][64][256][32] tiled
    short* qws   = (short*)(base + 0x800000);           // 1 MB   [B][256 grp][512] packed
    short* kws   = (short*)(base + 0x900000);           // 1 MB   [B][256 grp][512] packed
    float* pl    = (float*)(base + 0xA00000);           // 256 KB [4][B*N]
    short* Wall  = (short*)(base + 0xA40000);           // 160 KB fragment-packed
    float* ball  = (float*)(base + 0xA68000);           // 1.25 KB
    short* pnum  = (short*)(base + 0xB00000);           // 24 MB  [3][B][256][N]

    prep_kernel<<<41, 256, 0, stream>>>(Wq, bq, Wk, bk, Wv, bv, Wall, ball);
    proj_kernel<<<dim3(N_ / 64, B_), 1024, 0, stream>>>(x, Wall, ball, qws, kws, vws);
    attn_kernel<<<512, 512, 0, stream>>>(qws, kws, vws, out, pnum, pl);
    combine_kernel<<<4096, 256, 0, stream>>>(pnum, pl, x, gamma, out);
}

// Round 13
// 143.127 us; speedup vs baseline: 1.0388x; 1.0388x over previous
//
#include <hip/hip_runtime.h>

#define B_   4
#define C_   256
#define C8_  32
#define N_   4096
#define JS   2                 // key split: js0 -> fp32 in d_out, js1 -> bf16 pnum1
#define NJ   (N_ / JS)         // 2048 keys per attn block
#define KB2  128               // j per tile
#define NT2  (NJ / KB2)        // 16 j-tiles per attn block
#define SUBT 8192              // shorts per V subtile: 256 c x 32 j
#define BCN  ((size_t)B_ * C_ * N_)   // 4,194,304

typedef __attribute__((ext_vector_type(8))) short bf16x8;
typedef __attribute__((ext_vector_type(4))) float f32x4;

__device__ inline short f2bf(float f) {
    union { float f; unsigned u; } v; v.f = f;
    unsigned r = v.u + 0x7FFFu + ((v.u >> 16) & 1u);   // RNE
    return (short)(r >> 16);
}
__device__ inline float bf2f(short s) {
    union { unsigned u; float f; } v; v.u = ((unsigned)(unsigned short)s) << 16;
    return v.f;
}

// ---------------------------------------------------------------------------
// Kernel 0: prep (tiny). blocks [0,40): W fp32 -> fragment-packed Wall.
// block 40: bias gather ball[320]. (Unchanged from R10/R11 bench.)
// ---------------------------------------------------------------------------
__global__ __launch_bounds__(256) void prep_kernel(
    const float* __restrict__ Wq, const float* __restrict__ bq,
    const float* __restrict__ Wk, const float* __restrict__ bk,
    const float* __restrict__ Wv, const float* __restrict__ bv,
    short* __restrict__ Wall, float* __restrict__ ball)
{
    const int blk = blockIdx.x;
    const int t   = threadIdx.x;
    if (blk < 40) {
        const int base = blk * 2048 + t * 8;            // 40*2048 = 320*256
        const int r = base >> 8, cc = base & 255;       // cc is 8-aligned
        const float* src = (r < 32) ? &Wq[r * C_ + cc]
                         : (r < 64) ? &Wk[(r - 32) * C_ + cc]
                                    : &Wv[(r - 64) * C_ + cc];
        const float4 a  = *(const float4*)src;
        const float4 b4 = *(const float4*)(src + 4);
        short4 s1, s2;
        s1.x = f2bf(a.x);  s1.y = f2bf(a.y);  s1.z = f2bf(a.z);  s1.w = f2bf(a.w);
        s2.x = f2bf(b4.x); s2.y = f2bf(b4.y); s2.z = f2bf(b4.z); s2.w = f2bf(b4.w);
        const int gct = r >> 4, l16w = r & 15;
        const int k   = cc >> 5, quad = (cc >> 3) & 3;
        short* d = &Wall[(((size_t)(gct * 8 + k) * 4 + quad) * 16 + l16w) * 8];
        *(short4*)d       = s1;
        *(short4*)(d + 4) = s2;
    } else {
        for (int i = t; i < 320; i += 256)
            ball[i] = (i < 32) ? bq[i] : (i < 64) ? bk[i - 32] : bv[i - 64];
    }
}

// ---------------------------------------------------------------------------
// Kernel 1: FUSED transpose + MFMA projections (unchanged from R10/R11 bench).
// ---------------------------------------------------------------------------
#define VSTORE(A, CT)                                                         \
  {                                                                           \
    const int co   = (CT) * 16 + l16;                                         \
    const float bs = ball[co];                                                \
    const int nb   = n0 + nw * 16 + quad * 4;                                 \
    const int js   = nb >> 11, sub = (nb >> 5) & 63, jj = nb & 31;            \
    short4 s;                                                                 \
    s.x = f2bf(A[0] + bs); s.y = f2bf(A[1] + bs);                             \
    s.z = f2bf(A[2] + bs); s.w = f2bf(A[3] + bs);                             \
    *(short4*)&vws[((size_t)((b * 2 + js) * 64 + sub)) * SUBT                 \
                   + (co - 64) * 32 + jj] = s;                                \
  }

__global__ __launch_bounds__(1024) void proj_kernel(
    const float* __restrict__ x, const short* __restrict__ Wall,
    const float* __restrict__ ball,
    short* __restrict__ qws, short* __restrict__ kws, short* __restrict__ vws)
{
    __shared__ short tilebf[256 * 68];   // 34.8 KB

    const int n0 = blockIdx.x * 64;
    const int b  = blockIdx.y;
    const int t  = threadIdx.x;
    const int w  = t >> 6, lane = t & 63, l16 = lane & 15, quad = lane >> 4;
    const int nw = w & 3, qtr = w >> 2;

    // phase 1: x (fp32) -> bf16 LDS tile [c][nl], 4 float4 per thread
    const float* xb = x + (size_t)b * C_ * N_ + n0;
    #pragma unroll
    for (int i = 0; i < 4; i++) {
        int e = t + i * 1024;                // 4096 float4 = 256 rows x 16
        int c = e >> 4, n4 = (e & 15) * 4;
        float4 v = *(const float4*)(xb + (size_t)c * N_ + n4);
        short4 s;
        s.x = f2bf(v.x); s.y = f2bf(v.y); s.z = f2bf(v.z); s.w = f2bf(v.w);
        *(short4*)&tilebf[c * 68 + n4] = s;
    }
    __syncthreads();

    // phase 2: bfr fragments (n = n0 + nw*16 + l16; c = k*32 + quad*8 + j)
    bf16x8 bfr[8];
    const int nl = nw * 16 + l16;
    #pragma unroll
    for (int k = 0; k < 8; k++) {
        bf16x8 f;
        #pragma unroll
        for (int j = 0; j < 8; j++)
            f[j] = tilebf[(k * 32 + quad * 8 + j) * 68 + nl];
        bfr[k] = f;
    }

    f32x4 acc[5];
    #pragma unroll
    for (int i = 0; i < 5; i++) acc[i] = (f32x4){0.f, 0.f, 0.f, 0.f};

    if (qtr == 0) {
        #pragma unroll
        for (int k = 0; k < 8; k++) {
            const bf16x8 bk = bfr[k];
            #pragma unroll
            for (int c5 = 0; c5 < 4; c5++) {
                const bf16x8 af = *(const bf16x8*)
                    &Wall[(size_t)(c5 * 8 + k) * 512 + lane * 8];
                acc[c5] = __builtin_amdgcn_mfma_f32_16x16x32_bf16(af, bk, acc[c5], 0, 0, 0);
            }
            const bf16x8 af4 = *(const bf16x8*)
                &Wall[(size_t)(4 * 8 + k) * 512 + lane * 8];
            acc[4] = __builtin_amdgcn_mfma_f32_16x16x32_bf16(bk, af4, acc[4], 0, 0, 0);
        }
    } else {
        const int ct0 = qtr * 5;
        #pragma unroll
        for (int k = 0; k < 8; k++) {
            const bf16x8 bk = bfr[k];
            #pragma unroll
            for (int c5 = 0; c5 < 5; c5++) {
                const bf16x8 af = *(const bf16x8*)
                    &Wall[(size_t)((ct0 + c5) * 8 + k) * 512 + lane * 8];
                acc[c5] = __builtin_amdgcn_mfma_f32_16x16x32_bf16(bk, af, acc[c5], 0, 0, 0);
            }
        }
    }

    const int grp = (n0 >> 4) + nw;          // = n>>4 for this wave

    if (qtr == 0) {
        #pragma unroll
        for (int ct = 0; ct < 2; ct++) {
            const int cb = ct * 16 + quad * 4;
            short4 s;
            s.x = f2bf(acc[ct][0] + ball[cb + 0]);
            s.y = f2bf(acc[ct][1] + ball[cb + 1]);
            s.z = f2bf(acc[ct][2] + ball[cb + 2]);
            s.w = f2bf(acc[ct][3] + ball[cb + 3]);
            *(short4*)&qws[((size_t)(b * 256 + grp)) * 512
                           + (ct * 2 + (quad >> 1)) * 128 + l16 * 8 + (quad & 1) * 4] = s;
        }
        #pragma unroll
        for (int ct = 2; ct < 4; ct++) {
            const int cb = ct * 16 + quad * 4;
            short4 s;
            s.x = f2bf(acc[ct][0] + ball[cb + 0]);
            s.y = f2bf(acc[ct][1] + ball[cb + 1]);
            s.z = f2bf(acc[ct][2] + ball[cb + 2]);
            s.w = f2bf(acc[ct][3] + ball[cb + 3]);
            *(short4*)&kws[((size_t)(b * 256 + grp)) * 512
                           + ((ct - 2) * 2 + (quad >> 1)) * 128 + l16 * 8 + (quad & 1) * 4] = s;
        }
        VSTORE(acc[4], 4);
    } else {
        const int ct0 = qtr * 5;
        #pragma unroll
        for (int c5 = 0; c5 < 5; c5++) VSTORE(acc[c5], ct0 + c5);
    }
}

// ---------------------------------------------------------------------------
// Kernel 2: MFMA flash attention, v14 = v12 (48.9us benched) with a
// SOFTWARE-PIPELINED tile body. v12 budget closed as a SUM of phases
// (LDS 2600 + VALU 2400 + V 1150 + MFMA 690 ~= 7330 cy measured): each
// wave issues PV[t] fully before exp[t+1] (program order) and all waves
// are in the same phase -> pipes serialize. Fix: after barrier[t], do
// QK[t+1] (register-only) FIRST, then interleave PV[t]'s 4 ks-clusters
// with exp[t+1]'s 4 jf-pair chunks, writing P[t+1] to the other buffer.
// Same single lgkm-only barrier per tile; same buffer-safety argument
// (PV[t-1] reads of buf^1 complete before barrier[t] for all waves);
// per-accumulator MFMA chain order and operand values unchanged ->
// numerics identical. js=2 (v13's 4-way split regressed on traffic).
// ---------------------------------------------------------------------------
#define EXPW(J, BUF)                                                          \
  {                                                                           \
    float p0 = __expf(s[J][0]); float p1 = __expf(s[J][1]);                   \
    float p2 = __expf(s[J][2]); float p3 = __expf(s[J][3]);                   \
    lsum += p0 + p1 + p2 + p3;                                                \
    short4 pa; pa.x = f2bf(p0); pa.y = f2bf(p1);                              \
    pa.z = f2bf(p2); pa.w = f2bf(p3);                                         \
    const int u = ((J) * 2 + (quad >> 1)) ^ swz;                              \
    *(short4*)&Plds[(BUF) ^ 1][prowW + u * 8] = pa;                           \
  }

#define PVKS(KS, VF, BUF)                                                     \
  {                                                                           \
    __builtin_amdgcn_s_setprio(1);                                            \
    _Pragma("unroll") for (int qt = 0; qt < 8; ++qt) {                        \
      const bf16x8 pf = *(const bf16x8*)                                      \
        &Plds[BUF][(qt*16+l16)*128 + (((KS)*4+quad)^swz)*8];                  \
      _Pragma("unroll") for (int ct = 0; ct < 2; ++ct)                        \
        acc[ct][qt] = __builtin_amdgcn_mfma_f32_16x16x32_bf16(                \
            VF[ct], pf, acc[ct][qt], 0, 0, 0);                                \
    }                                                                         \
    __builtin_amdgcn_s_setprio(0);                                            \
  }

// PV of tile T (reads Plds[BUF]); QK+exp of tile T+1 (writes Plds[BUF^1]).
// KC holds K[T+1]; prefetch K[T+2] into KN.
#define PIPE_BODY(T, KC, KN, BUF)                                             \
  {                                                                           \
    const short* vb = vbase + (size_t)(T) * 4 * SUBT;                         \
    bf16x8 vf0[2], vf1[2];                                                    \
    _Pragma("unroll") for (int ct = 0; ct < 2; ct++)                          \
      vf0[ct] = *(const bf16x8*)(vb + 0 * SUBT + (ct*16+l16)*32 + quad*8);    \
    _Pragma("unroll") for (int ct = 0; ct < 2; ct++)                          \
      vf1[ct] = *(const bf16x8*)(vb + 1 * SUBT + (ct*16+l16)*32 + quad*8);    \
    /* QK for tile T+1: register-only, feeds the interleaved exp below */     \
    f32x4 s[8];                                                               \
    _Pragma("unroll") for (int jf = 0; jf < 8; jf++)                          \
      s[jf] = __builtin_amdgcn_mfma_f32_16x16x32_bf16(KC[jf], qf,             \
              (f32x4){0.f,0.f,0.f,0.f}, 0, 0, 0);                             \
    /* K prefetch for tile T+2 (clamped) */                                   \
    {                                                                         \
      const int tn = ((T) + 2 < NT2) ? (T) + 2 : NT2 - 1;                     \
      const short* kb = kfb + (size_t)(tn * 8) * 512;                         \
      _Pragma("unroll") for (int jf = 0; jf < 8; jf++)                        \
        KN[jf] = *(const bf16x8*)(kb + (size_t)jf * 512 + lane * 8);          \
    }                                                                         \
    /* interleave: PV[T] ks-cluster || exp[T+1] jf-pair (separate pipes) */   \
    PVKS(0, vf0, BUF);                                                        \
    EXPW(0, BUF); EXPW(1, BUF);                                               \
    bf16x8 vf2[2];                                                            \
    _Pragma("unroll") for (int ct = 0; ct < 2; ct++)                          \
      vf2[ct] = *(const bf16x8*)(vb + 2 * SUBT + (ct*16+l16)*32 + quad*8);    \
    PVKS(1, vf1, BUF);                                                        \
    EXPW(2, BUF); EXPW(3, BUF);                                               \
    bf16x8 vf3[2];                                                            \
    _Pragma("unroll") for (int ct = 0; ct < 2; ct++)                          \
      vf3[ct] = *(const bf16x8*)(vb + 3 * SUBT + (ct*16+l16)*32 + quad*8);    \
    PVKS(2, vf2, BUF);                                                        \
    EXPW(4, BUF); EXPW(5, BUF);                                               \
    PVKS(3, vf3, BUF);                                                        \
    EXPW(6, BUF); EXPW(7, BUF);                                               \
    /* publish P[T+1]; vmcnt stays in flight (lgkm-only barrier, v8-proven)*/ \
    asm volatile("s_waitcnt lgkmcnt(0)" ::: "memory");                        \
    __builtin_amdgcn_s_barrier();                                             \
    asm volatile("" ::: "memory");                                            \
  }

__global__ __launch_bounds__(512, 1) void attn_kernel(
    const short* __restrict__ qws, const short* __restrict__ kws,
    const short* __restrict__ vws,
    float* __restrict__ out, short* __restrict__ pnum1, float* __restrict__ pl)
{
    __shared__ short Plds[2][128 * 128];   // 2 x 32 KB

    const int blk = blockIdx.x;
    const int b   = blk & 3;
    const int js  = (blk >> 2) & 1;
    const int qc  = blk >> 3;            // 0..31, 128 q each
    const int t   = threadIdx.x;
    const int w   = t >> 6, lane = t & 63, l16 = lane & 15, quad = lane >> 4;
    const int q   = qc * 128 + w * 16 + l16;   // QK-duty q row for this lane

    // Q from fragment-packed qws: group qc*8+w, contiguous 1KB per wave
    const bf16x8 qf = *(const bf16x8*)
        &qws[((size_t)(b * 256 + qc * 8 + w)) * 512 + lane * 8];

    f32x4 acc[2][8];                     // PV: wave owns c [32w,32w+32) x 128 q
    #pragma unroll
    for (int i = 0; i < 2; i++)
        #pragma unroll
        for (int j = 0; j < 8; j++) acc[i][j] = (f32x4){0.f, 0.f, 0.f, 0.f};
    float lsum = 0.f;

    // fragment-packed K base for this (b, js): groups js*128 + tile*8 + jf
    const short* kfb = kws + ((size_t)(b * 256 + js * 128)) * 512;
    // tiled V: this wave's c-slice [32w, 32w+32) within each subtile
    const short* vbase = vws + ((size_t)((b * 2 + js) * 64)) * SUBT + w * 32 * 32;

    // swizzle: 16B unit u' = u ^ (row&7); row&7 == l16&7 for write and reads
    const int swz   = l16 & 7;
    const int prowW = (w * 16 + l16) * 128 + (quad & 1) * 4;   // + u'*8

    bf16x8 kfA[8], kfB[8];

    // prologue: QK[0] -> exp[0] -> P[0] into Plds[0]; kfA then holds K[1]
    #pragma unroll
    for (int jf = 0; jf < 8; jf++)
        kfA[jf] = *(const bf16x8*)(kfb + (size_t)jf * 512 + lane * 8);
    {
        f32x4 s[8];
        #pragma unroll
        for (int jf = 0; jf < 8; jf++)
            s[jf] = __builtin_amdgcn_mfma_f32_16x16x32_bf16(kfA[jf], qf,
                    (f32x4){0.f, 0.f, 0.f, 0.f}, 0, 0, 0);
        #pragma unroll
        for (int jf = 0; jf < 8; jf++)
            kfA[jf] = *(const bf16x8*)(kfb + (size_t)(8 + jf) * 512 + lane * 8);
        #pragma unroll
        for (int jf = 0; jf < 8; jf++) {
            float p0 = __expf(s[jf][0]); float p1 = __expf(s[jf][1]);
            float p2 = __expf(s[jf][2]); float p3 = __expf(s[jf][3]);
            lsum += p0 + p1 + p2 + p3;
            short4 pa; pa.x = f2bf(p0); pa.y = f2bf(p1);
            pa.z = f2bf(p2); pa.w = f2bf(p3);
            const int u = (jf * 2 + (quad >> 1)) ^ swz;
            *(short4*)&Plds[0][prowW + u * 8] = pa;
        }
        asm volatile("s_waitcnt lgkmcnt(0)" ::: "memory");
        __builtin_amdgcn_s_barrier();
        asm volatile("" ::: "memory");
    }

    // steady state: 7 pairs (T=0..13) + T=14; each body: PV[T] + produce P[T+1]
    #pragma unroll 1
    for (int tile = 0; tile < 14; tile += 2) {
        PIPE_BODY(tile,     kfA, kfB, 0);
        PIPE_BODY(tile + 1, kfB, kfA, 1);
    }
    PIPE_BODY(14, kfA, kfB, 0);

    // epilogue: PV[15] from Plds[1] (no further QK/exp)
    {
        const short* vb = vbase + (size_t)15 * 4 * SUBT;
        bf16x8 vf0[2], vf1[2], vf2[2], vf3[2];
        #pragma unroll
        for (int ct = 0; ct < 2; ct++)
            vf0[ct] = *(const bf16x8*)(vb + 0 * SUBT + (ct*16+l16)*32 + quad*8);
        #pragma unroll
        for (int ct = 0; ct < 2; ct++)
            vf1[ct] = *(const bf16x8*)(vb + 1 * SUBT + (ct*16+l16)*32 + quad*8);
        #pragma unroll
        for (int ct = 0; ct < 2; ct++)
            vf2[ct] = *(const bf16x8*)(vb + 2 * SUBT + (ct*16+l16)*32 + quad*8);
        #pragma unroll
        for (int ct = 0; ct < 2; ct++)
            vf3[ct] = *(const bf16x8*)(vb + 3 * SUBT + (ct*16+l16)*32 + quad*8);
        PVKS(0, vf0, 1);
        PVKS(1, vf1, 1);
        PVKS(2, vf2, 1);
        PVKS(3, vf3, 1);
    }

    // denominator partial for this wave's q over its full j half
    lsum += __shfl_xor(lsum, 16, 64);
    lsum += __shfl_xor(lsum, 32, 64);
    if (quad == 0) pl[(size_t)js * 16384 + (size_t)b * N_ + q] = lsum;

    // numerator partial: js0 -> fp32 into out, js1 -> bf16 into pnum1
    const int qq = qc * 128 + l16;
    if (js == 0) {
        float* ob = out + (size_t)b * C_ * N_;
        #pragma unroll
        for (int ct = 0; ct < 2; ++ct)
            #pragma unroll
            for (int qt = 0; qt < 8; ++qt)
                #pragma unroll
                for (int r = 0; r < 4; ++r) {
                    const int c = w * 32 + ct * 16 + quad * 4 + r;
                    ob[(size_t)c * N_ + qq + qt * 16] = acc[ct][qt][r];
                }
    } else {
        short* pb1 = pnum1 + (size_t)b * C_ * N_;
        #pragma unroll
        for (int ct = 0; ct < 2; ++ct)
            #pragma unroll
            for (int qt = 0; qt < 8; ++qt)
                #pragma unroll
                for (int r = 0; r < 4; ++r) {
                    const int c = w * 32 + ct * 16 + quad * 4 + r;
                    pb1[(size_t)c * N_ + qq + qt * 16] = f2bf(acc[ct][qt][r]);
                }
    }
}

// ---------------------------------------------------------------------------
// Kernel 3: combine (lred fused): linv = 1/(pl0+pl1) inline.
// out = g*(out + pnum1)*linv + x.
// ---------------------------------------------------------------------------
__global__ __launch_bounds__(256) void combine_kernel(
    const short* __restrict__ pnum1, const float* __restrict__ pl,
    const float* __restrict__ x, const float* __restrict__ gamma,
    float* __restrict__ out)
{
    const size_t i4 = ((size_t)blockIdx.x * 256 + threadIdx.x) * 4;   // < BCN
    const float4 nv = *(const float4*)(out + i4);
    const short4 n1 = *(const short4*)(pnum1 + i4);
    const float4 xv = *(const float4*)(x + i4);
    const int   bn  = (int)((i4 >> 20) * 4096 + (i4 & 4095));         // b*N + n
    const float4 p0 = *(const float4*)(pl + bn);
    const float4 p1 = *(const float4*)(pl + 16384 + bn);
    float4 lv;
    lv.x = 1.0f / (p0.x + p1.x);
    lv.y = 1.0f / (p0.y + p1.y);
    lv.z = 1.0f / (p0.z + p1.z);
    lv.w = 1.0f / (p0.w + p1.w);
    const float g0 = gamma[0];
    float4 o;
    o.x = g0 * ((nv.x + bf2f(n1.x)) * lv.x) + xv.x;
    o.y = g0 * ((nv.y + bf2f(n1.y)) * lv.y) + xv.y;
    o.z = g0 * ((nv.z + bf2f(n1.z)) * lv.z) + xv.z;
    o.w = g0 * ((nv.w + bf2f(n1.w)) * lv.w) + xv.w;
    *(float4*)(out + i4) = o;
}

extern "C" void kernel_launch(void* const* d_in, const int* in_sizes, int n_in,
                              void* d_out, int out_size, void* d_ws, size_t ws_size,
                              hipStream_t stream)
{
    const float* x     = (const float*)d_in[0];
    const float* Wq    = (const float*)d_in[1];
    const float* bq    = (const float*)d_in[2];
    const float* Wk    = (const float*)d_in[3];
    const float* bk    = (const float*)d_in[4];
    const float* Wv    = (const float*)d_in[5];
    const float* bv    = (const float*)d_in[6];
    const float* gamma = (const float*)d_in[7];
    float* out = (float*)d_out;

    // ws layout (R11-proven region sizes).
    char* base = (char*)d_ws;
    short* vws   = (short*)(base);                      // 8 MB  [8][64][256][32] tiled
    short* qws   = (short*)(base + 0x800000);           // 1 MB  [B][256 grp][512] packed
    short* kws   = (short*)(base + 0x900000);           // 1 MB  [B][256 grp][512] packed
    float* pl    = (float*)(base + 0xA00000);           // 128 KB [2][B*N]
    short* Wall  = (short*)(base + 0xA30000);           // 160 KB fragment-packed
    float* ball  = (float*)(base + 0xA58000);           // 1.25 KB
    short* pnum1 = (short*)(base + 0xA60000);           // 8 MB  [B][256][N]

    prep_kernel<<<41, 256, 0, stream>>>(Wq, bq, Wk, bk, Wv, bv, Wall, ball);
    proj_kernel<<<dim3(N_ / 64, B_), 1024, 0, stream>>>(x, Wall, ball, qws, kws, vws);
    attn_kernel<<<256, 512, 0, stream>>>(qws, kws, vws, out, pnum1, pl);
    combine_kernel<<<4096, 256, 0, stream>>>(pnum1, pl, x, gamma, out);
}